// Round 7
// baseline (176.967 us; speedup 1.0000x reference)
//
#include <hip/hip_runtime.h>
#include <hip/hip_bf16.h>
#include <stdint.h>

// VQ: x [N=131072, D=64] fp32, E [D=64, K=1024] fp32.
// R12: TLP fix. R9/R10/R11 ablation: three different B-delivery schemes all
// land 94-108 us -> B path is not the constraint; the invariant is grid 1024
// = 4 blocks/CU -> ~2.4 resident waves/SIMD, too few to hide the per-tile
// serial chain (vmcnt -> ds -> 6-deep MFMA -> min-update). Fix: 128-thread
// blocks (2 waves, 64 rows), grid 2048 -> 8 blocks/CU, 4 waves/SIMD, finer
// tail. Loop body is R9's verbatim (best measured: pinned reg-prefetch +
// sched_barrier + unroll 2). Screen math + fused fp64 refine identical.
// Verified facts used: A[m=lane&15][k=(lane>>4)*8+j] (m89/m91/m120),
// C/D col=lane&15 row=(lane>>4)*4+reg (m89/m91), frag types short8/float4.

typedef unsigned long long u64;
typedef short short8 __attribute__((ext_vector_type(8)));
typedef float f32x4 __attribute__((ext_vector_type(4)));

constexpr int D = 64;
constexpr int K = 1024;
constexpr float TAU = 1e-3f;

__device__ __forceinline__ unsigned short bf16_rne(float v) {
    uint32_t u = __float_as_uint(v);
    uint32_t r = u + 0x7FFFu + ((u >> 16) & 1u);
    return (unsigned short)(r >> 16);
}
__device__ __forceinline__ float bf16_f(unsigned short h) {
    return __uint_as_float(((uint32_t)h) << 16);
}
// monotone fp32 -> u32 map (min preserved) — R3-proven
__device__ __forceinline__ uint32_t fmap(float v) {
    uint32_t u = __float_as_uint(v);
    return (u & 0x80000000u) ? ~u : (u | 0x80000000u);
}
__device__ __forceinline__ float funmap(uint32_t m) {
    uint32_t u = (m & 0x80000000u) ? (m ^ 0x80000000u) : ~m;
    return __uint_as_float(u);
}
__device__ __forceinline__ void top2_merge(u64& b, u64& s, u64 ob, u64 os) {
    if (ob < b) { s = (b < os) ? b : os; b = ob; }
    else        { s = (ob < s) ? ob : s; }
}
__device__ __forceinline__ u64 shfl_xor_u64(u64 v, int m) {
    uint32_t lo = (uint32_t)v, hi = (uint32_t)(v >> 32);
    lo = (uint32_t)__shfl_xor((int)lo, m, 64);
    hi = (uint32_t)__shfl_xor((int)hi, m, 64);
    return ((u64)hi << 32) | lo;
}
__device__ __forceinline__ double shfl_xor_f64(double v, int m) {
    int lo = __double2loint(v), hi = __double2hiint(v);
    lo = __shfl_xor(lo, m, 64);
    hi = __shfl_xor(hi, m, 64);
    return __hiloint2double(hi, lo);
}
// 8 fp32 -> bf16 hi + residual-lo fragments (in-register, no LDS transpose)
__device__ __forceinline__ void cvt8(float4 a, float4 b, short8& H, short8& L) {
    float v[8] = {a.x, a.y, a.z, a.w, b.x, b.y, b.z, b.w};
    #pragma unroll
    for (int e = 0; e < 8; ++e) {
        unsigned short h = bf16_rne(v[e]);
        H[e] = (short)h;
        L[e] = (short)bf16_rne(v[e] - bf16_f(h));
    }
}

// ---- prep: e_sq (f64/f32), ET[k][d] gather table, Bhi/Blo fragment-linear
//      bf16 tables of -2E (hi + residual lo). grid 256 x 256. ----
__global__ __launch_bounds__(256) void vq_prep(const float* __restrict__ E,
                                               double* __restrict__ e_sq64,
                                               float* __restrict__ e_sq32,
                                               float* __restrict__ ET,
                                               unsigned short* __restrict__ Bhi,
                                               unsigned short* __restrict__ Blo) {
    int tid = blockIdx.x * 256 + threadIdx.x;        // 0..65535
    if (tid < K) {
        int k = tid;
        double s = 0.0;
        for (int d = 0; d < D; ++d) {
            float v = E[d * K + k];
            s = fma((double)v, (double)v, s);
            ET[k * D + d] = v;
        }
        e_sq64[k] = s;
        e_sq32[k] = (float)s;
    }
    // table entry: frag f = t*2+c (t=tile 0..63, c=k-chunk 0..1), lane l, slot j
    //   value = -2*E[d][code], d = 32c + 8*(l>>4) + j, code = 16t + (l&15)
    {
        int j = tid & 7;
        int l = (tid >> 3) & 63;
        int f = tid >> 9;            // 0..127
        int c = f & 1;
        int t = f >> 1;
        int d = 32 * c + 8 * (l >> 4) + j;
        int code = 16 * t + (l & 15);
        float v = -2.0f * E[d * K + code];
        unsigned short h = bf16_rne(v);
        Bhi[tid] = h;
        Blo[tid] = bf16_rne(v - bf16_f(h));
    }
}

// ---- screen + fused exact refine: block = 64 rows (2 waves x 32) ----
__global__ __launch_bounds__(128, 4) void vq_screen(
    const float* __restrict__ x,
    const short8* __restrict__ Bh, const short8* __restrict__ Bl,
    const float* __restrict__ e_sq32, const double* __restrict__ e_sq64,
    const float* __restrict__ ET, float* __restrict__ out) {
    __shared__ float esq[K];                   // 4 KB
    __shared__ int bk[64];                     // 0.25 KB
    __shared__ double xs64[D];                 // 0.5 KB (refine staging)
    __shared__ double wbv[2];
    __shared__ int wbk_s[2];
    __shared__ int flag_list[64];              // 0.25 KB
    __shared__ int flag_n;

    const int t0 = threadIdx.x;
    const int base = blockIdx.x * 64;

    if (t0 == 0) flag_n = 0;

    // stage e_sq (128 threads x 8)
    #pragma unroll
    for (int i = 0; i < 8; ++i) esq[i * 128 + t0] = e_sq32[i * 128 + t0];

    const int wid = t0 >> 6, l = t0 & 63;      // wid in {0,1}
    const int col = l & 15, quad = l >> 4;

    // A fragments for 2 rowsets, loaded DIRECTLY from global in fragment order
    // (verified layout: m = lane&15, k = quad*8 + j, k-chunks at 0 and 32).
    const int gr0 = base + wid * 32 + col;     // rowset a global row
    short8 Ah0a, Ah1a, Al0a, Al1a, Ah0b, Ah1b, Al0b, Al1b;
    {
        const float* xr = x + (size_t)gr0 * D + quad * 8;
        float4 p0 = *(const float4*)(xr);
        float4 p1 = *(const float4*)(xr + 4);
        float4 p2 = *(const float4*)(xr + 32);
        float4 p3 = *(const float4*)(xr + 36);
        const float* xs = xr + 16 * D;         // rowset b
        float4 q0 = *(const float4*)(xs);
        float4 q1 = *(const float4*)(xs + 4);
        float4 q2 = *(const float4*)(xs + 32);
        float4 q3 = *(const float4*)(xs + 36);
        cvt8(p0, p1, Ah0a, Al0a);
        cvt8(p2, p3, Ah1a, Al1a);
        cvt8(q0, q1, Ah0b, Al0b);
        cvt8(q2, q3, Ah1b, Al1b);
    }

    float besta[4], seca[4], bestb[4], secb[4];
    int bidxa[4], bidxb[4];
    #pragma unroll
    for (int r = 0; r < 4; ++r) {
        besta[r] = 3.4e38f; seca[r] = 3.4e38f; bidxa[r] = 0;
        bestb[r] = 3.4e38f; secb[r] = 3.4e38f; bidxb[r] = 0;
    }

    short8 bh0 = Bh[l], bh1 = Bh[64 + l];
    short8 bl0 = Bl[l], bl1 = Bl[64 + l];

    __syncthreads();   // esq + flag_n ready

    float esv_c = esq[col];                    // tile 0 e_sq value

    #pragma unroll 2
    for (int t = 0; t < 64; ++t) {
        // prefetch next tile's B frags + e_sq (t=63 wraps to 0 — valid, unused)
        int fb = ((t + 1) & 63) * 128 + l;
        short8 nh0 = Bh[fb], nh1 = Bh[fb + 64];
        short8 nl0 = Bl[fb], nl1 = Bl[fb + 64];
        float esv_n = esq[((t + 1) & 63) * 16 + col];
        // pin: loads above may not sink below, MFMAs below may not hoist above
        // (R8: without this the compiler sinks the loads -> per-tile L2 stall).
        __builtin_amdgcn_sched_barrier(0);

        f32x4 Ca = {esv_c, esv_c, esv_c, esv_c};
        f32x4 Cb = {esv_c, esv_c, esv_c, esv_c};
        // single chain per rowset; a/b chains independent -> ILP for the pipe
        Ca = __builtin_amdgcn_mfma_f32_16x16x32_bf16(Ah0a, bh0, Ca, 0, 0, 0);
        Cb = __builtin_amdgcn_mfma_f32_16x16x32_bf16(Ah0b, bh0, Cb, 0, 0, 0);
        Ca = __builtin_amdgcn_mfma_f32_16x16x32_bf16(Ah1a, bh1, Ca, 0, 0, 0);
        Cb = __builtin_amdgcn_mfma_f32_16x16x32_bf16(Ah1b, bh1, Cb, 0, 0, 0);
        Ca = __builtin_amdgcn_mfma_f32_16x16x32_bf16(Ah0a, bl0, Ca, 0, 0, 0);
        Cb = __builtin_amdgcn_mfma_f32_16x16x32_bf16(Ah0b, bl0, Cb, 0, 0, 0);
        Ca = __builtin_amdgcn_mfma_f32_16x16x32_bf16(Ah1a, bl1, Ca, 0, 0, 0);
        Cb = __builtin_amdgcn_mfma_f32_16x16x32_bf16(Ah1b, bl1, Cb, 0, 0, 0);
        Ca = __builtin_amdgcn_mfma_f32_16x16x32_bf16(Al0a, bh0, Ca, 0, 0, 0);
        Cb = __builtin_amdgcn_mfma_f32_16x16x32_bf16(Al0b, bh0, Cb, 0, 0, 0);
        Ca = __builtin_amdgcn_mfma_f32_16x16x32_bf16(Al1a, bh1, Ca, 0, 0, 0);
        Cb = __builtin_amdgcn_mfma_f32_16x16x32_bf16(Al1b, bh1, Cb, 0, 0, 0);

        int tc = t * 16;
        #pragma unroll
        for (int r = 0; r < 4; ++r) {
            float va = Ca[r];
            bool lta = va < besta[r];
            float mxa = fmaxf(va, besta[r]);
            besta[r] = fminf(va, besta[r]);
            seca[r]  = fminf(seca[r], mxa);
            bidxa[r] = lta ? tc : bidxa[r];
            float vb = Cb[r];
            bool ltb = vb < bestb[r];
            float mxb = fmaxf(vb, bestb[r]);
            bestb[r] = fminf(vb, bestb[r]);
            secb[r]  = fminf(secb[r], mxb);
            bidxb[r] = ltb ? tc : bidxb[r];
        }
        bh0 = nh0; bh1 = nh1; bl0 = nl0; bl1 = nl1;
        esv_c = esv_n;
    }

    // per-register reduce across the 16 col-lanes (masks 1..8 preserve quad)
    #pragma unroll
    for (int r = 0; r < 4; ++r) {
        {   // rowset a
            u64 b = ((u64)fmap(besta[r]) << 32) | (uint32_t)(bidxa[r] + col);
            u64 s = ((u64)fmap(seca[r]) << 32) | 0xFFFFFFFFu;
            #pragma unroll
            for (int m = 8; m >= 1; m >>= 1) {
                u64 ob = shfl_xor_u64(b, m);
                u64 os = shfl_xor_u64(s, m);
                top2_merge(b, s, ob, os);
            }
            if (col == 0) {
                int rowL = wid * 32 + quad * 4 + r;       // verified C row map
                bk[rowL] = (int)(uint32_t)(b & 0xFFFFFFFFu);
                float vb = funmap((uint32_t)(b >> 32));
                float vs = funmap((uint32_t)(s >> 32));
                if (vs - vb < TAU) {
                    int idx = atomicAdd(&flag_n, 1);
                    flag_list[idx] = rowL;
                }
            }
        }
        {   // rowset b
            u64 b = ((u64)fmap(bestb[r]) << 32) | (uint32_t)(bidxb[r] + col);
            u64 s = ((u64)fmap(secb[r]) << 32) | 0xFFFFFFFFu;
            #pragma unroll
            for (int m = 8; m >= 1; m >>= 1) {
                u64 ob = shfl_xor_u64(b, m);
                u64 os = shfl_xor_u64(s, m);
                top2_merge(b, s, ob, os);
            }
            if (col == 0) {
                int rowL = wid * 32 + 16 + quad * 4 + r;
                bk[rowL] = (int)(uint32_t)(b & 0xFFFFFFFFu);
                float vb = funmap((uint32_t)(b >> 32));
                float vs = funmap((uint32_t)(s >> 32));
                if (vs - vb < TAU) {
                    int idx = atomicAdd(&flag_n, 1);
                    flag_list[idx] = rowL;
                }
            }
        }
    }
    __syncthreads();

    // fused exact refine for flagged rows (rare: ~0.016 rows/block expected).
    // Identical math + tie-breaks to the proven refine: ET[k*D+d] == E[d*K+k]
    // exactly; fp64 fma over ascending d; v<best with ascending k (thread t0
    // owns k in [8*t0, 8*t0+8), waves own disjoint ascending ranges); wave
    // reduce then cross-wave lowest-k-on-tie merge.
    {
        int nf = flag_n;                         // uniform across block
        for (int f = 0; f < nf; ++f) {
            int rowR = flag_list[f];
            if (t0 < D) xs64[t0] = (double)x[(size_t)(base + rowR) * D + t0];
            __syncthreads();
            double best = 1.0e300; int bestk = 0;
            #pragma unroll
            for (int j = 0; j < 8; ++j) {
                int k = t0 * 8 + j;
                const float* ep = ET + (size_t)k * D;
                double a = 0.0;
                #pragma unroll 4
                for (int d = 0; d < D; ++d)
                    a = fma(xs64[d], (double)ep[d], a);
                double v = fma(-2.0, a, e_sq64[k]);
                if (v < best) { best = v; bestk = k; }
            }
            #pragma unroll
            for (int m = 32; m >= 1; m >>= 1) {
                double ov = shfl_xor_f64(best, m);
                int    ok = __shfl_xor(bestk, m, 64);
                if (ov < best || (ov == best && ok < bestk)) { best = ov; bestk = ok; }
            }
            if ((t0 & 63) == 0) { wbv[t0 >> 6] = best; wbk_s[t0 >> 6] = bestk; }
            __syncthreads();
            if (t0 == 0) {
                double bv = wbv[0]; int bb = wbk_s[0];
                if (wbv[1] < bv || (wbv[1] == bv && wbk_s[1] < bb)) { bv = wbv[1]; bb = wbk_s[1]; }
                bk[rowR] = bb;
            }
            __syncthreads();
        }
    }

    // gather: thread t0 copies 128 B of its row from ET
    {
        int row = t0 >> 1, seg = t0 & 1;
        const float4* ep = (const float4*)(ET + (size_t)bk[row] * D + seg * 32);
        float4* op = (float4*)(out + (size_t)(base + row) * D + seg * 32);
        #pragma unroll
        for (int q = 0; q < 8; ++q) op[q] = ep[q];
    }
}

extern "C" void kernel_launch(void* const* d_in, const int* in_sizes, int n_in,
                              void* d_out, int out_size, void* d_ws, size_t ws_size,
                              hipStream_t stream) {
    const float* x = (const float*)d_in[0];
    const float* E = (const float*)d_in[1];
    float* out = (float*)d_out;
    int N = in_sizes[0] / D;   // 131072

    // ws: e_sq64 8K | e_sq32 4K | ET 256K | Bhi 128K | Blo 128K
    char* w = (char*)d_ws;
    double*         e_sq64 = (double*)w;          w += K * sizeof(double);
    float*          e_sq32 = (float*)w;           w += K * sizeof(float);
    float*          ET     = (float*)w;           w += (size_t)K * D * sizeof(float);
    unsigned short* Bhi    = (unsigned short*)w;  w += (size_t)K * D * sizeof(unsigned short);
    unsigned short* Blo    = (unsigned short*)w;  w += (size_t)K * D * sizeof(unsigned short);

    vq_prep<<<256, 256, 0, stream>>>(E, e_sq64, e_sq32, ET, Bhi, Blo);
    vq_screen<<<N / 64, 128, 0, stream>>>(x, (const short8*)Bhi, (const short8*)Blo,
                                          e_sq32, e_sq64, ET, out);
}